// Round 2
// baseline (297.968 us; speedup 1.0000x reference)
//
#include <hip/hip_runtime.h>
#include <hip/hip_bf16.h>

// NLinear: out[b,f,o] = sum_i x[b,f,i] * w[f,i,o] + bias[f,o]
// B=8192, F=64, I=128, O=128, fp32. Memory-bound: ~540MB min traffic -> ~85us floor.
// Structure: W^T staged once per block in LDS (bf16, XOR-swizzled); X fragments
// loaded DIRECTLY from global (x has no reuse -> LDS staging was pure overhead).
// No barriers in the main loop. Swapped MFMA operands (D[o][b]) give dwordx4 stores.

#define NF 64
#define DI 128
#define DO 128
#define BM 128
#define TILES 4
#define CHUNKS 16            // 8192 / (128*4)
#define RS (NF * DI)         // 8192 floats: row stride of x and out

typedef __attribute__((ext_vector_type(8))) short short8;
typedef __attribute__((ext_vector_type(4))) float floatx4;

// round-to-nearest-even f32 -> bf16 bits
static __device__ __forceinline__ unsigned short f2bf(float f) {
    union { float f; unsigned u; } v; v.f = f;
    unsigned r = v.u + 0x7fffu + ((v.u >> 16) & 1u);
    return (unsigned short)(r >> 16);
}

__global__ __launch_bounds__(256, 3)
void nlinear_kernel(const float* __restrict__ x,
                    const float* __restrict__ w,
                    const float* __restrict__ bias,
                    float* __restrict__ out) {
    // W^T bf16, swizzled: element (o,i) at byte o*256 + ((i*2) ^ ((o&15)<<4)).
    // Fragment reads (16 consecutive o, same k-offset) hit 16 distinct 16B slots
    // -> conflict-free. Transpose writes are 8-way but happen once per block.
    __shared__ unsigned short lds_wt[DO * DI];   // 32 KB
    __shared__ float lds_bias[DO];

    // Bijective XCD swizzle (grid=1024 % 8 == 0): 8 features per XCD, each
    // feature's 16 chunks on one XCD -> W_f (64KB) L2-resident.
    int b = blockIdx.x;
    int logical = (b & 7) * (NF * CHUNKS / 8) + (b >> 3);
    int f = logical >> 4;          // 0..63
    int chunk = logical & 15;      // 0..15

    int tid  = threadIdx.x;
    int lane = tid & 63;
    int wid  = tid >> 6;           // 0..3

    // ---- stage W^T (coalesced float4 reads, bf16 swizzled scatter writes) ----
    const float* wf = w + (size_t)f * DI * DO;
    #pragma unroll
    for (int it = 0; it < 16; ++it) {
        int id = it * 256 + tid;
        int i  = id >> 5;              // k index 0..127
        int o4 = (id & 31) << 2;       // output-col group
        floatx4 v = *(const floatx4*)(wf + i * DO + o4);
        #pragma unroll
        for (int j = 0; j < 4; ++j) {
            int o = o4 + j;
            int byte = o * 256 + ((i * 2) ^ ((o & 15) << 4));
            *(unsigned short*)((char*)lds_wt + byte) = f2bf(v[j]);
        }
    }
    if (tid < DO) lds_bias[tid] = bias[f * DO + tid];
    __syncthreads();   // the only barrier: lds_wt/lds_bias read-only below

    int lrow = lane & 15;          // A-row (=o sub-index) / B-col (=batch row)
    int kq   = lane >> 4;          // k-quarter 0..3

    // bias fragment, lane-constant: acc reg j holds o = n*16 + kq*4 + j
    floatx4 bias4[8];
    #pragma unroll
    for (int n = 0; n < 8; ++n)
        bias4[n] = *(const floatx4*)(lds_bias + n * 16 + kq * 4);

    for (int t = 0; t < TILES; ++t) {
        int row0 = (chunk * TILES + t) * BM + wid * 32;   // this wave's 32 rows

        floatx4 acc[2][8];
        #pragma unroll
        for (int m = 0; m < 2; ++m)
            #pragma unroll
            for (int n = 0; n < 8; ++n)
                acc[m][n] = bias4[n];      // C-in = bias

        #pragma unroll
        for (int kk = 0; kk < 4; ++kk) {
            // X fragments direct from global: lane reads 32B contiguous;
            // wave covers 16 rows x 128B full cache lines.
            short8 ax[2];
            #pragma unroll
            for (int m = 0; m < 2; ++m) {
                const float* p = x + (size_t)(row0 + m * 16 + lrow) * RS
                                   + f * DI + kk * 32 + kq * 8;
                floatx4 v0 = *(const floatx4*)p;
                floatx4 v1 = *(const floatx4*)(p + 4);
                short8 a;
                a[0] = (short)f2bf(v0[0]); a[1] = (short)f2bf(v0[1]);
                a[2] = (short)f2bf(v0[2]); a[3] = (short)f2bf(v0[3]);
                a[4] = (short)f2bf(v1[0]); a[5] = (short)f2bf(v1[1]);
                a[6] = (short)f2bf(v1[2]); a[7] = (short)f2bf(v1[3]);
                ax[m] = a;
            }
            int kb = kk * 64 + kq * 16;    // byte offset of this lane's k-group
            #pragma unroll
            for (int n = 0; n < 8; ++n) {
                int o = n * 16 + lrow;
                short8 bw = *(const short8*)((const char*)lds_wt
                              + o * 256 + (kb ^ ((o & 15) << 4)));
                // D = W^T x X  -> D[row=o][col=b]: col=lane&15=batch row,
                // row=(lane>>4)*4+reg=o  => lane holds 4 consecutive o.
                acc[0][n] = __builtin_amdgcn_mfma_f32_16x16x32_bf16(
                                bw, ax[0], acc[0][n], 0, 0, 0);
                acc[1][n] = __builtin_amdgcn_mfma_f32_16x16x32_bf16(
                                bw, ax[1], acc[1][n], 0, 0, 0);
            }
        }

        // ---- epilogue: one dwordx4 per (m,n); quarter-wave writes 16 rows x 64B ----
        #pragma unroll
        for (int m = 0; m < 2; ++m) {
            float* op = out + (size_t)(row0 + m * 16 + lrow) * RS
                            + f * DO + kq * 4;
            #pragma unroll
            for (int n = 0; n < 8; ++n)
                *(floatx4*)(op + n * 16) = acc[m][n];
        }
    }
}

extern "C" void kernel_launch(void* const* d_in, const int* in_sizes, int n_in,
                              void* d_out, int out_size, void* d_ws, size_t ws_size,
                              hipStream_t stream) {
    const float* x    = (const float*)d_in[0];
    const float* wght = (const float*)d_in[1];
    const float* bias = (const float*)d_in[2];
    float* out        = (float*)d_out;

    dim3 grid(NF * CHUNKS);   // 1024
    dim3 block(256);
    nlinear_kernel<<<grid, block, 0, stream>>>(x, wght, bias, out);
}

// Round 3
// 238.164 us; speedup vs baseline: 1.2511x; 1.2511x over previous
//
#include <hip/hip_runtime.h>
#include <hip/hip_bf16.h>

// NLinear: out[b,f,o] = sum_i x[b,f,i] * w[f,i,o] + bias[f,o]
// B=8192, F=64, I=128, O=128, fp32. Memory-bound: 540MB min -> ~86us floor.
//
// R3 structure: W^T bf16 in LDS (staged once/block, XOR-swizzled); X loaded
// direct from global through an explicit 2-tile register pipeline (16
// outstanding dwordx4 per wave) -- fixes R2's serialized-load latency wall.
// Out written with nontemporal dwordx4 (no L2/L3 allocation -> no RMW fetch,
// no L3 pollution so x stays L3-resident). No barriers in the main loop.

#define NF 64
#define DI 128
#define DO 128
#define BM 128
#define TILES 4
#define CHUNKS 16            // 8192 / (128*4)
#define RS (NF * DI)         // 8192 floats: row stride of x and out

typedef __attribute__((ext_vector_type(8))) short short8;
typedef __attribute__((ext_vector_type(4))) float floatx4;

struct RawTile { floatx4 v[16]; };   // [m*8 + kk*2 + h] : one 128-row tile's x slice

// round-to-nearest-even f32 -> bf16 bits
static __device__ __forceinline__ unsigned short f2bf(float f) {
    union { float f; unsigned u; } v; v.f = f;
    unsigned r = v.u + 0x7fffu + ((v.u >> 16) & 1u);
    return (unsigned short)(r >> 16);
}

__global__ __launch_bounds__(256, 2)
void nlinear_kernel(const float* __restrict__ x,
                    const float* __restrict__ w,
                    const float* __restrict__ bias,
                    float* __restrict__ out) {
    // W^T bf16, swizzled: element (o,i) at byte o*256 + ((i*2) ^ ((o&15)<<4)).
    __shared__ unsigned short lds_wt[DO * DI];   // 32 KB
    __shared__ float lds_bias[DO];

    // Bijective XCD swizzle (grid=1024 % 8 == 0): each feature's 16 chunks on
    // one XCD -> W_f stays L2-resident.
    int b = blockIdx.x;
    int logical = (b & 7) * (NF * CHUNKS / 8) + (b >> 3);
    int f = logical >> 4;          // 0..63
    int chunk = logical & 15;      // 0..15

    int tid  = threadIdx.x;
    int lane = tid & 63;
    int wid  = tid >> 6;           // 0..3
    int lrow = lane & 15;          // batch-row sub-index / o sub-index
    int kq   = lane >> 4;          // k-quarter 0..3

    // ---- stage W^T (coalesced float4 reads, bf16 swizzled scatter writes) ----
    const float* wf = w + (size_t)f * DI * DO;
    #pragma unroll
    for (int it = 0; it < 16; ++it) {
        int id = it * 256 + tid;
        int i  = id >> 5;              // k index 0..127
        int o4 = (id & 31) << 2;       // output-col group
        floatx4 v = *(const floatx4*)(wf + i * DO + o4);
        #pragma unroll
        for (int j = 0; j < 4; ++j) {
            int o = o4 + j;
            int byte = o * 256 + ((i * 2) ^ ((o & 15) << 4));
            *(unsigned short*)((char*)lds_wt + byte) = f2bf(v[j]);
        }
    }
    if (tid < DO) lds_bias[tid] = bias[f * DO + tid];

    // per-lane base pointers (tile 0)
    const float* xw = x + ((size_t)(chunk * TILES) * BM + wid * 32 + lrow) * RS
                        + f * DI + kq * 8;
    float* ow = out + ((size_t)(chunk * TILES) * BM + wid * 32 + lrow) * RS
                    + f * DO + kq * 4;

    RawTile ra, rb;

    auto load_tile = [&](RawTile& r, int t) {
        const float* p = xw + (size_t)t * BM * RS;
        #pragma unroll
        for (int m = 0; m < 2; ++m)
            #pragma unroll
            for (int kk = 0; kk < 4; ++kk)
                #pragma unroll
                for (int h = 0; h < 2; ++h)
                    r.v[m * 8 + kk * 2 + h] =
                        *(const floatx4*)(p + m * 16 * RS + kk * 32 + h * 4);
    };

    auto compute_store = [&](const RawTile& r, int t) {
        // bias fragment: acc reg j holds o = n*16 + kq*4 + j
        floatx4 acc[2][8];
        #pragma unroll
        for (int n = 0; n < 8; ++n) {
            floatx4 bv = *(const floatx4*)(lds_bias + n * 16 + kq * 4);
            acc[0][n] = bv;
            acc[1][n] = bv;
        }
        // convert raw f32 -> bf16 fragments
        short8 ax[2][4];
        #pragma unroll
        for (int m = 0; m < 2; ++m)
            #pragma unroll
            for (int kk = 0; kk < 4; ++kk) {
                floatx4 v0 = r.v[m * 8 + kk * 2];
                floatx4 v1 = r.v[m * 8 + kk * 2 + 1];
                short8 a;
                a[0] = (short)f2bf(v0[0]); a[1] = (short)f2bf(v0[1]);
                a[2] = (short)f2bf(v0[2]); a[3] = (short)f2bf(v0[3]);
                a[4] = (short)f2bf(v1[0]); a[5] = (short)f2bf(v1[1]);
                a[6] = (short)f2bf(v1[2]); a[7] = (short)f2bf(v1[3]);
                ax[m][kk] = a;
            }
        // MFMA: D = W^T x X -> D[o][batch]; lane holds 4 consecutive o
        #pragma unroll
        for (int kk = 0; kk < 4; ++kk) {
            int kb = (kk * 64 + kq * 16) ^ (lrow << 4);
            #pragma unroll
            for (int n = 0; n < 8; ++n) {
                short8 bw = *(const short8*)((const char*)lds_wt
                              + (n * 16 + lrow) * 256 + kb);
                acc[0][n] = __builtin_amdgcn_mfma_f32_16x16x32_bf16(
                                bw, ax[0][kk], acc[0][n], 0, 0, 0);
                acc[1][n] = __builtin_amdgcn_mfma_f32_16x16x32_bf16(
                                bw, ax[1][kk], acc[1][n], 0, 0, 0);
            }
        }
        // nontemporal dwordx4 stores (4 lanes x 16B = 64B contiguous per row)
        #pragma unroll
        for (int m = 0; m < 2; ++m) {
            float* op = ow + (size_t)t * BM * RS + m * 16 * RS;
            #pragma unroll
            for (int n = 0; n < 8; ++n)
                __builtin_nontemporal_store(acc[m][n], (floatx4*)(op + n * 16));
        }
    };

    load_tile(ra, 0);        // overlap with W staging + barrier
    __syncthreads();         // lds_wt / lds_bias ready (read-only after)

    load_tile(rb, 1);
    compute_store(ra, 0);
    load_tile(ra, 2);
    compute_store(rb, 1);
    load_tile(rb, 3);
    compute_store(ra, 2);
    compute_store(rb, 3);
}

extern "C" void kernel_launch(void* const* d_in, const int* in_sizes, int n_in,
                              void* d_out, int out_size, void* d_ws, size_t ws_size,
                              hipStream_t stream) {
    const float* x    = (const float*)d_in[0];
    const float* wght = (const float*)d_in[1];
    const float* bias = (const float*)d_in[2];
    float* out        = (float*)d_out;

    dim3 grid(NF * CHUNKS);   // 1024
    dim3 block(256);
    nlinear_kernel<<<grid, block, 0, stream>>>(x, wght, bias, out);
}

// Round 4
// 181.542 us; speedup vs baseline: 1.6413x; 1.3119x over previous
//
#include <hip/hip_runtime.h>
#include <hip/hip_bf16.h>

// NLinear: out[b,f,o] = sum_i x[b,f,i] * w[f,i,o] + bias[f,o]
// B=8192, F=64, I=128, O=128, fp32. ~540MB min traffic -> ~86us floor.
//
// R4: TLP-first. Wave owns 16 rows (small acc), 256-thr block = 64-row tile,
// 4 tiles/block, grid 2048. W^T bf16 in LDS (32.5KB only) -> 4 blocks/CU ->
// 16 waves/CU (50% occ). Per tile each wave batch-issues 8 independent
// dwordx4 x-loads then converts+MFMAs. No barriers in main loop, no
// register pipeline to fight the allocator: latency hidden by waves.

#define NF 64
#define DI 128
#define DO 128
#define WROWS 16             // rows per wave
#define BMT (WROWS * 4)      // 64 rows per block-tile (4 waves)
#define TILES 4
#define CHUNKS 32            // 8192 / (64*4)
#define RS (NF * DI)         // 8192 floats: row stride of x and out

typedef __attribute__((ext_vector_type(8))) short short8;
typedef __attribute__((ext_vector_type(4))) float floatx4;

// round-to-nearest-even f32 -> bf16 bits
static __device__ __forceinline__ unsigned short f2bf(float f) {
    union { float f; unsigned u; } v; v.f = f;
    unsigned r = v.u + 0x7fffu + ((v.u >> 16) & 1u);
    return (unsigned short)(r >> 16);
}

__global__ __launch_bounds__(256, 4)
void nlinear_kernel(const float* __restrict__ x,
                    const float* __restrict__ w,
                    const float* __restrict__ bias,
                    float* __restrict__ out) {
    // W^T bf16, swizzled: element (o,i) at byte o*256 + ((i*2) ^ ((o&15)<<4)).
    // Fragment reads hit 16 distinct 16B slots per quarter -> ~2-way max (free).
    __shared__ unsigned short lds_wt[DO * DI];   // 32 KB
    __shared__ float lds_bias[DO];               // 512 B

    // Bijective XCD swizzle (grid=2048 % 8 == 0): 8 features per XCD ->
    // W_f (64KB f32) stays L2-resident for all 32 of its chunks.
    int b = blockIdx.x;
    int logical = (b & 7) * (NF * CHUNKS / 8) + (b >> 3);
    int f = logical >> 5;          // 0..63
    int chunk = logical & 31;      // 0..31

    int tid  = threadIdx.x;
    int lane = tid & 63;
    int wid  = tid >> 6;           // 0..3
    int lrow = lane & 15;          // batch-row sub-index (B-col) / o sub-index
    int kq   = lane >> 4;          // k-quarter 0..3

    // ---- stage W^T (coalesced float4 reads, bf16 swizzled scatter writes) ----
    const float* wf = w + (size_t)f * DI * DO;
    #pragma unroll
    for (int it = 0; it < 16; ++it) {
        int id = it * 256 + tid;
        int i  = id >> 5;              // k index 0..127
        int o4 = (id & 31) << 2;       // output-col group
        floatx4 v = *(const floatx4*)(wf + i * DO + o4);
        #pragma unroll
        for (int j = 0; j < 4; ++j) {
            int o = o4 + j;
            int byte = o * 256 + ((i * 2) ^ ((o & 15) << 4));
            *(unsigned short*)((char*)lds_wt + byte) = f2bf(v[j]);
        }
    }
    if (tid < DO) lds_bias[tid] = bias[f * DO + tid];
    __syncthreads();   // the only barrier; lds_wt/lds_bias read-only below

    // per-lane base pointers (row = this wave's lrow-th row of tile 0)
    size_t row0 = (size_t)chunk * (BMT * TILES) + wid * WROWS + lrow;
    const float* xw = x   + row0 * RS + f * DI;
    float*       ow = out + row0 * RS + f * DO + kq * 4;

    for (int t = 0; t < TILES; ++t) {
        const float* xp = xw + (size_t)t * BMT * RS;

        // ---- batch-issue 8 independent dwordx4 loads (8KB/wave in flight) ----
        floatx4 raw[8];
        #pragma unroll
        for (int kk = 0; kk < 4; ++kk)
            #pragma unroll
            for (int h = 0; h < 2; ++h)
                raw[kk * 2 + h] = *(const floatx4*)(xp + kk * 32 + kq * 8 + h * 4);

        // ---- convert to bf16 A-operands ----
        short8 ax[4];
        #pragma unroll
        for (int kk = 0; kk < 4; ++kk) {
            floatx4 v0 = raw[kk * 2], v1 = raw[kk * 2 + 1];
            short8 a;
            a[0] = (short)f2bf(v0[0]); a[1] = (short)f2bf(v0[1]);
            a[2] = (short)f2bf(v0[2]); a[3] = (short)f2bf(v0[3]);
            a[4] = (short)f2bf(v1[0]); a[5] = (short)f2bf(v1[1]);
            a[6] = (short)f2bf(v1[2]); a[7] = (short)f2bf(v1[3]);
            ax[kk] = a;
        }

        // ---- acc init = bias (reg j holds o = n*16 + kq*4 + j) ----
        floatx4 acc[8];
        #pragma unroll
        for (int n = 0; n < 8; ++n)
            acc[n] = *(const floatx4*)(lds_bias + n * 16 + kq * 4);

        // ---- MFMA: D = W^T x X -> D[o][batch]; lane holds 4 consecutive o ----
        #pragma unroll
        for (int kk = 0; kk < 4; ++kk) {
            int kb = (kk * 64 + kq * 16) ^ (lrow << 4);
            #pragma unroll
            for (int n = 0; n < 8; ++n) {
                short8 bw = *(const short8*)((const char*)lds_wt
                              + (n * 16 + lrow) * 256 + kb);
                acc[n] = __builtin_amdgcn_mfma_f32_16x16x32_bf16(
                             bw, ax[kk], acc[n], 0, 0, 0);
            }
        }

        // ---- stores: per instr 16 rows x 64B contiguous segments ----
        float* op = ow + (size_t)t * BMT * RS;
        #pragma unroll
        for (int n = 0; n < 8; ++n)
            *(floatx4*)(op + n * 16) = acc[n];
    }
}

extern "C" void kernel_launch(void* const* d_in, const int* in_sizes, int n_in,
                              void* d_out, int out_size, void* d_ws, size_t ws_size,
                              hipStream_t stream) {
    const float* x    = (const float*)d_in[0];
    const float* wght = (const float*)d_in[1];
    const float* bias = (const float*)d_in[2];
    float* out        = (float*)d_out;

    dim3 grid(NF * CHUNKS);   // 2048
    dim3 block(256);
    nlinear_kernel<<<grid, block, 0, stream>>>(x, wght, bias, out);
}